// Round 2
// baseline (746.727 us; speedup 1.0000x reference)
//
#include <hip/hip_runtime.h>
#include <hip/hip_bf16.h>

// Problem constants (from reference)
#define NN 16384
#define EE 65536
#define DD 64
#define HH 128
#define LL 3
#define GG 512
#define OUTD 128
#define NEG 0.01f   // jax.nn.leaky_relu default slope

// v6.1: fused S-build + GEMM. S never touches HBM.
// Contraction index c in [0,8192) per layer: c = ks*1024 + d*16 + il,
// with k_hidden = ks*16 + il (il in [0,16), d in [0,64), ks in [0,8)).
// W2T' is baked in this order: W2T'[l][f][c] = W2[l][ks*16+il][d*64+f].
// k_fused: block = 32 nodes; per ks-round: build S_tile[32][1024] bf16 in LDS
// (lane = d, ug scalar/wave-uniform), then MFMA vs W2T' fragments from global,
// accumulating out[32][64] in VGPRs across all rounds. Writes num fp32 once.
// Fix vs v6: B-operand stride was kst*2 short8s (16 shorts); each kstep is 32
// contraction cols -> must be kst*4.

typedef __attribute__((ext_vector_type(8))) short short8;
typedef __attribute__((ext_vector_type(4))) float f32x4;

__device__ __forceinline__ float leaky(float x){ return x > 0.f ? x : NEG * x; }
__device__ __forceinline__ unsigned short f2bf(float f){
  union { float f; unsigned int u; } v; v.f = f;
  unsigned int r = v.u + 0x7fffu + ((v.u >> 16) & 1u);   // RNE
  return (unsigned short)(r >> 16);
}

#define CV_A (EE*DD)            // 4194304
#define CV_B (LL*HH*DD)         // 24576
#define CV_C (LL*64*8192)       // 1572864
#define PRE0 (NN/4)             // init_ln blocks
#define PRE1 ((CV_A+CV_B+CV_C)/256)
#define PRE2 (EE/256)

// ---------------- merged pre-kernel: init+LN0 | bf16 conversions | deg/cnt ----------------
__global__ void k_pre(const float* x_in, const float* ln_s, const float* ln_b,
                      float* x_cur, float* h, int* deg, int* cursor, int* cnt, float* pooled,
                      const float* ea, const float* W1, const float* W2,
                      unsigned short* eab, unsigned short* W1T, unsigned short* W2T,
                      const int* ei, const int* batch){
  int t = threadIdx.x;
  int b = blockIdx.x;
  if (b < PRE0){
    int i = b*256 + t;
    if (i < NN){ deg[i] = 0; cursor[i] = 0; }
    if (i < GG) cnt[i] = 0;
    if (i < GG*DD) pooled[i] = 0.f;
    int lane = t & 63, nl = t >> 6;
    int n = b*4 + nl;
    float v = x_in[(size_t)n*DD + lane];
    x_cur[(size_t)n*DD + lane] = v;
    float s = v;
    for (int m=1;m<64;m<<=1) s += __shfl_xor(s, m, 64);
    float mu = s * (1.0f/64.0f);
    float dv = v - mu;
    float q = dv*dv;
    for (int m=1;m<64;m<<=1) q += __shfl_xor(q, m, 64);
    float var = q * (1.0f/64.0f);
    float w = dv * rsqrtf(var + 1e-5f) * ln_s[lane] + ln_b[lane];
    h[(size_t)n*DD + lane] = leaky(w);
    return;
  }
  if (b < PRE0 + PRE1){
    int idx = (b - PRE0)*256 + t;
    if (idx < CV_A){
      eab[idx] = f2bf(ea[idx]);
    } else if (idx < CV_A + CV_B){
      int i = idx - CV_A;
      int l = i >> 13, r = i & 8191;
      int j = r >> 6, d = r & 63;
      W1T[i] = f2bf(W1[(size_t)l*DD*HH + d*HH + j]);   // W1T[l][j][d]
    } else {
      int i = idx - CV_A - CV_B;
      int l = i >> 19, rem = i & ((1<<19)-1);          // 64*8192 per layer
      int f = rem >> 13, c = rem & 8191;               // W2T'[l][f][c]
      int ks = c >> 10, cl = c & 1023;
      int d = cl >> 4, il = cl & 15;
      int kh = ks*16 + il;                             // hidden index in [0,128)
      W2T[i] = f2bf(W2[(size_t)l*HH*DD*DD + (size_t)kh*DD*DD + (size_t)d*DD + f]);
    }
    return;
  }
  {
    int e = (b - PRE0 - PRE1)*256 + t;
    atomicAdd(&deg[ei[EE + e]], 1);          // row 1 of edge_index = dst
    if (e < NN) atomicAdd(&cnt[batch[e]], 1);
  }
}

__global__ void k_scan(const int* deg, int* row_ptr){
  __shared__ int part[256];
  int t = threadIdx.x;
  int base = t*64; int s = 0;
  for (int i=0;i<64;++i) s += deg[base+i];
  part[t] = s; __syncthreads();
  for (int off=1; off<256; off<<=1){
    int v = (t>=off)?part[t-off]:0; __syncthreads();
    part[t] += v; __syncthreads();
  }
  int run = (t==0)?0:part[t-1];
  if (t==0) row_ptr[0] = 0;
  for (int i=0;i<64;++i){ run += deg[base+i]; row_ptr[base+i+1] = run; }
}
__global__ void k_fill(const int* ei, const int* row_ptr, int* cursor,
                       int* edge_id, int* src_sorted){
  int e = blockIdx.x*256 + threadIdx.x;
  if (e < EE){
    int d = ei[EE + e];
    int pos = row_ptr[d] + atomicAdd(&cursor[d], 1);
    edge_id[pos] = e;
    src_sorted[pos] = ei[e];      // row 0 of edge_index = src
  }
}

// ---------------- edge MLP (ALL 3 layers, CSR-sorted order): ug[l][pos] ----------------------
__global__ __launch_bounds__(256, 2)
void k_mlp3(const unsigned short* eab, const unsigned short* W1T, const float* b1,
            const int* edge_id, unsigned short* ug){
  __shared__ __align__(16) unsigned short a_lds[128][72];   // ea tile  [pos][d]
  __shared__ __align__(16) unsigned short b_lds[128][72];   // W1T      [j][d]
  __shared__ __align__(16) unsigned short c_lds[128][136];  // out      [pos][j]
  int t = threadIdx.x;
  int l  = blockIdx.x >> 9;                 // EE/128 = 512 blocks per layer
  int e0 = (blockIdx.x & 511) * 128;
  {
    int row = t >> 1, col = (t & 1) * 32;
    int eid = edge_id[e0 + row];
    const float4* sa = (const float4*)(eab + (size_t)eid*DD + col);
    const float4* sb = (const float4*)(W1T + (size_t)l*HH*DD + (size_t)row*DD + col);
    #pragma unroll
    for (int i=0;i<4;++i){
      *(float4*)&a_lds[row][col + 8*i] = sa[i];
      *(float4*)&b_lds[row][col + 8*i] = sb[i];
    }
  }
  __syncthreads();
  int wave = t >> 6, lane = t & 63;
  int m0 = (wave >> 1) * 64, j0 = (wave & 1) * 64;
  int lr = lane & 15, lq = lane >> 4;
  f32x4 acc[4][4];
  #pragma unroll
  for (int a=0;a<4;++a)
    #pragma unroll
    for (int b=0;b<4;++b) acc[a][b] = (f32x4){0.f,0.f,0.f,0.f};
  #pragma unroll
  for (int ks=0; ks<2; ++ks){
    short8 av[4];
    #pragma unroll
    for (int mt=0; mt<4; ++mt) av[mt] = *(const short8*)&a_lds[m0 + mt*16 + lr][ks*32 + lq*8];
    #pragma unroll
    for (int jt=0; jt<4; ++jt){
      short8 bv = *(const short8*)&b_lds[j0 + jt*16 + lr][ks*32 + lq*8];
      #pragma unroll
      for (int mt=0; mt<4; ++mt)
        acc[mt][jt] = __builtin_amdgcn_mfma_f32_16x16x32_bf16(av[mt], bv, acc[mt][jt], 0, 0, 0);
    }
  }
  // C/D: col = lane&15, row = (lane>>4)*4 + r
  #pragma unroll
  for (int mt=0; mt<4; ++mt)
    #pragma unroll
    for (int jt=0; jt<4; ++jt){
      int col = j0 + jt*16 + lr;
      float bj = b1[l*HH + col];
      #pragma unroll
      for (int r=0; r<4; ++r){
        int row = m0 + mt*16 + lq*4 + r;
        c_lds[row][col] = f2bf(leaky(acc[mt][jt][r] + bj));
      }
    }
  __syncthreads();
  {
    int row = t >> 1, half = t & 1;
    float4* dst = (float4*)(ug + (size_t)l*EE*HH + (size_t)(e0 + row)*HH + half*64);
    #pragma unroll
    for (int i=0;i<8;++i) dst[i] = *(const float4*)&c_lds[row][half*64 + 8*i];
  }
}

// ---------------- fused S-build + GEMM ----------------
// block = 32 nodes, 4 waves. Per ks-round (8 rounds of 1024 contraction cols):
//   build: wave w builds nodes [8w,8w+8): lane=d, acc[16] over il; ug vec loads.
//   S_tile LDS layout: byte = n*2048 + d*32 + il*2, XOR ((n&7)<<4)  (64 KB)
//   mfma:  wave w owns f-tile [16w,16w+16): 2 m-tiles x 32 ksteps; A from LDS,
//          B (W2T') from global (L2-resident, no cross-wave duplication).
// acc0/acc1 accumulate across all rounds; num written once (fp32).
#define ACC2(w, hv, base) { \
  float lo_ = __uint_as_float((w) << 16); \
  float hi_ = __uint_as_float((w) & 0xffff0000u); \
  acc[(base)]   += lo_*(hv); \
  acc[(base)+1] += hi_*(hv); }

#define EDGE_ACC(aa, bb, hv) \
  ACC2((aa).x, hv, 0)  ACC2((aa).y, hv, 2)  ACC2((aa).z, hv, 4)  ACC2((aa).w, hv, 6) \
  ACC2((bb).x, hv, 8)  ACC2((bb).y, hv,10)  ACC2((bb).z, hv,12)  ACC2((bb).w, hv,14)

__global__ __launch_bounds__(256)
void k_fused(const unsigned short* ug, const float* h, const int* row_ptr,
             const int* src_sorted, const unsigned short* W2T,
             float* num, float* Hs){
  __shared__ __align__(16) unsigned short Sm[32*1024];   // 64 KB
  char* Sb = (char*)Sm;
  int t = threadIdx.x, wave = t >> 6, lane = t & 63;
  int g0 = blockIdx.x * 32;
  int lr = lane & 15, lq = lane >> 4;
  int f0 = wave * 16;
  f32x4 acc0 = (f32x4){0.f,0.f,0.f,0.f};
  f32x4 acc1 = (f32x4){0.f,0.f,0.f,0.f};
  int wbase = (wave*8)*2048 + lane*32;          // build write base (node ni adds ni*2048)

  for (int ks = 0; ks < 8; ++ks){
    const unsigned short* ugk = ug + ks*16;
    // ---- build phase ----
    for (int ni = 0; ni < 8; ++ni){
      int n = g0 + wave*8 + ni;
      int r0 = row_ptr[n], r1 = row_ptr[n+1];
      float acc[16];
      #pragma unroll
      for (int i=0;i<16;++i) acc[i] = 0.f;
      float hs = 0.f;
      int pos = r0;
      for (; pos + 4 <= r1; pos += 4){
        int s0 = src_sorted[pos+0], s1 = src_sorted[pos+1];
        int s2 = src_sorted[pos+2], s3 = src_sorted[pos+3];
        const uint4* u0 = (const uint4*)(ugk + (size_t)(pos+0)*HH);
        const uint4* u1 = (const uint4*)(ugk + (size_t)(pos+1)*HH);
        const uint4* u2 = (const uint4*)(ugk + (size_t)(pos+2)*HH);
        const uint4* u3 = (const uint4*)(ugk + (size_t)(pos+3)*HH);
        float hv0 = h[(size_t)s0*DD + lane];
        float hv1 = h[(size_t)s1*DD + lane];
        float hv2 = h[(size_t)s2*DD + lane];
        float hv3 = h[(size_t)s3*DD + lane];
        uint4 a0 = u0[0], c0 = u0[1];
        uint4 a1 = u1[0], c1 = u1[1];
        uint4 a2 = u2[0], c2 = u2[1];
        uint4 a3 = u3[0], c3 = u3[1];
        hs += (hv0 + hv1) + (hv2 + hv3);
        EDGE_ACC(a0, c0, hv0)
        EDGE_ACC(a1, c1, hv1)
        EDGE_ACC(a2, c2, hv2)
        EDGE_ACC(a3, c3, hv3)
      }
      for (; pos < r1; ++pos){
        int s0 = src_sorted[pos];
        const uint4* u0 = (const uint4*)(ugk + (size_t)pos*HH);
        float hv0 = h[(size_t)s0*DD + lane];
        uint4 a0 = u0[0], c0 = u0[1];
        hs += hv0;
        EDGE_ACC(a0, c0, hv0)
      }
      // pack + write S row (2 x b128), swizzled
      unsigned int w[8];
      #pragma unroll
      for (int i=0;i<8;++i)
        w[i] = (unsigned int)f2bf(acc[2*i]) | ((unsigned int)f2bf(acc[2*i+1]) << 16);
      int nloc = wave*8 + ni;
      int off = (wbase + ni*2048) ^ ((nloc & 7) << 4);
      *(float4*)(Sb + off)        = *(const float4*)&w[0];
      *(float4*)(Sb + (off ^ 16)) = *(const float4*)&w[4];
      if (ks == 0) Hs[(size_t)n*DD + lane] = hs;
    }
    __syncthreads();
    // ---- mfma phase: f-tile per wave, 2 m-tiles, 32 ksteps ----
    {
      const short8* Wp = (const short8*)(W2T + (size_t)(f0 + lr)*8192 + (size_t)ks*1024 + lq*8);
      #pragma unroll
      for (int kst = 0; kst < 32; ++kst){
        short8 bv = Wp[kst*4];                       // 32 shorts per kstep
        int off = ((lr*2048 + lq*16 + kst*64) ^ ((lr&7)<<4));
        short8 a0 = *(const short8*)(Sb + off);
        short8 a1 = *(const short8*)(Sb + off + 32768);   // +16 nodes
        acc0 = __builtin_amdgcn_mfma_f32_16x16x32_bf16(a0, bv, acc0, 0, 0, 0);
        acc1 = __builtin_amdgcn_mfma_f32_16x16x32_bf16(a1, bv, acc1, 0, 0, 0);
      }
    }
    __syncthreads();
  }
  // C/D layout: col = lane&15 (f), row = (lane>>4)*4 + r (node)
  #pragma unroll
  for (int r=0; r<4; ++r){
    num[(size_t)(g0      + lq*4 + r)*DD + f0 + lr] = acc0[r];
    num[(size_t)(g0 + 16 + lq*4 + r)*DD + f0 + lr] = acc1[r];
  }
}

// ---------------- node update (+ fused next-layer LN), 16 nodes/block ----------------
__global__ void k_update_ln(float* x, const float* num, float* h, const float* Hs,
                            const int* deg, const float* root, const float* b2,
                            const float* conv_b, const float* ln_s, const float* ln_b,
                            int l, int do_ln){
  __shared__ float rl[64][64];
  __shared__ float b2l[64][64];
  __shared__ float hrow[4][64];
  __shared__ float hsrow[4][64];
  int t = threadIdx.x;
  int f = t & 63, nl = t >> 6;
  for (int idx=t; idx<4096; idx+=256){
    rl[idx>>6][idx&63]  = root[(size_t)l*4096 + idx];
    b2l[idx>>6][idx&63] = b2[(size_t)l*4096 + idx];
  }
  int nbase = blockIdx.x*16;
  float cb = conv_b[l*DD + f];
  for (int i=0;i<4;++i){
    int n = nbase + i*4 + nl;
    __syncthreads();              // covers staging (i=0) and prev-iter reads
    hrow[nl][f]  = h[(size_t)n*DD + f];
    hsrow[nl][f] = Hs[(size_t)n*DD + f];
    __syncthreads();
    float dg = (float)deg[n]; if (dg < 1.f) dg = 1.f;
    float nsum = num[(size_t)n*DD + f];
    float acc = x[(size_t)n*DD + f] + nsum/dg + cb;
    #pragma unroll
    for (int d=0; d<64; ++d)
      acc += hrow[nl][d]*rl[d][f] + hsrow[nl][d]*b2l[d][f];
    x[(size_t)n*DD + f] = acc;
    if (do_ln){
      int lp = l + 1;
      float s = acc;
      for (int m=1;m<64;m<<=1) s += __shfl_xor(s, m, 64);
      float mu = s * (1.0f/64.0f);
      float dv = acc - mu;
      float qv = dv*dv;
      for (int m=1;m<64;m<<=1) qv += __shfl_xor(qv, m, 64);
      float var = qv * (1.0f/64.0f);
      float w = dv * rsqrtf(var + 1e-5f) * ln_s[lp*DD + f] + ln_b[lp*DD + f];
      h[(size_t)n*DD + f] = leaky(w);
    }
  }
}

// ---------------- head: dense + pooled atomic accumulate, 16 nodes/block ----------------
__global__ void k_dense_pool(const float* x, const float* dW, const float* db,
                             const int* batch, float* pooled){
  __shared__ float wl[64][64];
  __shared__ float xrow[4][64];
  int t = threadIdx.x;
  int f = t & 63, nl = t >> 6;
  for (int idx=t; idx<4096; idx+=256) wl[idx>>6][idx&63] = dW[idx];
  int nbase = blockIdx.x*16;
  float dbf = db[f];
  for (int i=0;i<4;++i){
    int n = nbase + i*4 + nl;
    __syncthreads();
    xrow[nl][f] = x[(size_t)n*DD + f];
    __syncthreads();
    float acc = dbf;
    #pragma unroll
    for (int d=0; d<64; ++d) acc += xrow[nl][d]*wl[d][f];
    atomicAdd(&pooled[(size_t)batch[n]*DD + f], acc);
  }
}

__global__ void k_final(const float* pooled, const int* cnt, const float* oW,
                        const float* ob, float* out){
  __shared__ float p[64];
  int g = blockIdx.x, t = threadIdx.x;
  if (t < 64){
    float c = (float)cnt[g]; if (c < 1.f) c = 1.f;
    p[t] = leaky(pooled[(size_t)g*DD + t] / c);
  }
  __syncthreads();
  float acc = ob[t];
  #pragma unroll
  for (int f=0; f<64; ++f) acc += p[f]*oW[(size_t)f*OUTD + t];
  out[(size_t)g*OUTD + t] = acc;
}

// ws too small -> emit ws_size as diagnostic (deterministic per machine)
__global__ void k_diag(float* out, float val, int n){
  int i = blockIdx.x*256 + threadIdx.x;
  if (i < n) out[i] = (i==0) ? val : 0.f;
}

extern "C" void kernel_launch(void* const* d_in, const int* in_sizes, int n_in,
                              void* d_out, int out_size, void* d_ws, size_t ws_size,
                              hipStream_t stream){
  const float* x_in  = (const float*)d_in[0];
  const int*   ei    = (const int*)d_in[1];
  const float* ea    = (const float*)d_in[2];
  const int*   batch = (const int*)d_in[3];
  const float* ln_s  = (const float*)d_in[4];
  const float* ln_b  = (const float*)d_in[5];
  const float* W1    = (const float*)d_in[6];
  const float* b1    = (const float*)d_in[7];
  const float* W2    = (const float*)d_in[8];
  const float* b2    = (const float*)d_in[9];
  const float* root  = (const float*)d_in[10];
  const float* convb = (const float*)d_in[11];
  const float* dW    = (const float*)d_in[12];
  const float* db    = (const float*)d_in[13];
  const float* oW    = (const float*)d_in[14];
  const float* ob    = (const float*)d_in[15];
  float* out = (float*)d_out;

  char* ws = (char*)d_ws;
  size_t off = 0;
  auto alloc = [&](size_t bytes)->char*{
    char* p = ws + off; off = (off + bytes + 255) & ~(size_t)255; return p;
  };
  float* x_cur  = (float*)alloc((size_t)NN*DD*4);
  float* h      = (float*)alloc((size_t)NN*DD*4);
  unsigned short* ug  = (unsigned short*)alloc((size_t)LL*EE*HH*2);
  float* num    = (float*)alloc((size_t)NN*DD*4);
  float* Hs     = (float*)alloc((size_t)NN*DD*4);
  unsigned short* W2T = (unsigned short*)alloc((size_t)LL*8192*64*2);
  unsigned short* eab = (unsigned short*)alloc((size_t)EE*DD*2);
  unsigned short* W1T = (unsigned short*)alloc((size_t)LL*HH*DD*2);
  int* deg     = (int*)alloc((size_t)NN*4);
  int* row_ptr = (int*)alloc((size_t)(NN+1)*4);
  int* cursor  = (int*)alloc((size_t)NN*4);
  int* edge_id = (int*)alloc((size_t)EE*4);
  int* src_sorted = (int*)alloc((size_t)EE*4);
  int* cnt     = (int*)alloc((size_t)GG*4);
  float* pooled= (float*)alloc((size_t)GG*DD*4);
  size_t needed = off;
  if (ws_size < needed){
    k_diag<<<(out_size+255)/256, 256, 0, stream>>>(out, (float)ws_size, out_size);
    return;
  }

  k_pre <<<PRE0+PRE1+PRE2, 256, 0, stream>>>(x_in, ln_s, ln_b, x_cur, h, deg, cursor, cnt,
                                             pooled, ea, W1, W2, eab, W1T, W2T, ei, batch);
  k_scan<<<1, 256, 0, stream>>>(deg, row_ptr);
  k_fill<<<EE/256, 256, 0, stream>>>(ei, row_ptr, cursor, edge_id, src_sorted);
  k_mlp3<<<LL*(EE/128), 256, 0, stream>>>(eab, W1T, b1, edge_id, ug);

  for (int l=0; l<LL; ++l){
    k_fused<<<NN/32, 256, 0, stream>>>(ug + (size_t)l*EE*HH, h, row_ptr, src_sorted,
                                       W2T + (size_t)l*64*8192, num, Hs);
    k_update_ln<<<NN/16, 256, 0, stream>>>(x_cur, num, h, Hs, deg, root, b2, convb,
                                           ln_s, ln_b, l, (l < LL-1) ? 1 : 0);
  }
  k_dense_pool<<<NN/16, 256, 0, stream>>>(x_cur, dW, db, batch, pooled);
  k_final     <<<GG, 128, 0, stream>>>(pooled, cnt, oW, ob, out);
}